// Round 1
// baseline (463.865 us; speedup 1.0000x reference)
//
#include <hip/hip_runtime.h>
#include <hip/hip_bf16.h>

#define Hh 16
#define Dd 128
#define SEQ 2048
#define QB 64
#define KVB 32
#define ATT_SCALE 0.08838834764831845f

typedef float f32x4 __attribute__((ext_vector_type(4)));
typedef __bf16 bf16x8 __attribute__((ext_vector_type(8)));
typedef short s16x8 __attribute__((ext_vector_type(8)));

__device__ __forceinline__ ushort f2bf(float f) {
    uint u = __builtin_bit_cast(uint, f);
    uint r = (u + 0x7FFFu + ((u >> 16) & 1u)) >> 16;
    return (ushort)r;
}

__device__ __forceinline__ void cvt8(const float* __restrict__ s, ushort* __restrict__ d) {
    float4 a = *(const float4*)s;
    float4 b = *(const float4*)(s + 4);
    uint4 u;
    u.x = (uint)f2bf(a.x) | ((uint)f2bf(a.y) << 16);
    u.y = (uint)f2bf(a.z) | ((uint)f2bf(a.w) << 16);
    u.z = (uint)f2bf(b.x) | ((uint)f2bf(b.y) << 16);
    u.w = (uint)f2bf(b.z) | ((uint)f2bf(b.w) << 16);
    *(uint4*)d = u;
}

// ---- Kernel 1: copy cache[:T] rows into ws as bf16 (effective K/V base) ----
__global__ void conv_cache(const float* __restrict__ kc, const float* __restrict__ vc,
                           ushort* __restrict__ ek, ushort* __restrict__ ev, long n8) {
    long i = (long)blockIdx.x * blockDim.x + threadIdx.x;
    if (i >= n8) return;
    cvt8(kc + i * 8, ek + i * 8);
    cvt8(vc + i * 8, ev + i * 8);
}

// ---- Kernel 2: scatter k/v token rows into effective K/V at slot ----
__global__ void scatter_kv(const float* __restrict__ k, const float* __restrict__ v,
                           const int* __restrict__ slots,
                           ushort* __restrict__ ek, ushort* __restrict__ ev, int T) {
    int row = blockIdx.x;
    int s = slots[row];
    if (s < 0 || s >= T) return;  // slots >= T are stored in cache but never read
    int j = threadIdx.x;          // 256 threads x 8 elems = 2048 elems/row
    long src = (long)row * (Hh * Dd) + j * 8;
    long dst = (long)s * (Hh * Dd) + j * 8;
    cvt8(k + src, ek + dst);
    cvt8(v + src, ev + dst);
}

// ---- Kernel 3: causal flash attention, bf16 MFMA ----
__global__ __launch_bounds__(256) void attn(const float* __restrict__ q,
                                            const ushort* __restrict__ ek,
                                            const ushort* __restrict__ ev,
                                            float* __restrict__ out) {
    __shared__ ushort Kl[KVB][Dd + 8];       // 32 x 136  (pad -> ~2-way on b128 reads)
    __shared__ ushort Vt[Dd][KVB + 8];       // 128 x 40  (V transposed: Vt[d][key])
    __shared__ ushort Pl[4][16][KVB + 8];    // per-wave P buffer [q][key]

    const int tid = threadIdx.x;
    const int w = tid >> 6;
    const int lane = tid & 63;
    const int qq = lane >> 4;   // quarter-wave
    const int lr = lane & 15;
    const int bh = blockIdx.y;
    const int b = bh >> 4, h = bh & 15;
    const int qbase = blockIdx.x * QB;

    // ---- Q fragments (A operand): lane holds Q[q=lr][d = kk*32 + qq*8 + j] ----
    bf16x8 qf[4];
    {
        const int qrow = qbase + w * 16 + lr;
        const float* qp = q + ((long)(b * SEQ + qrow) * Hh + h) * Dd + qq * 8;
#pragma unroll
        for (int kk = 0; kk < 4; ++kk) {
            float4 a = *(const float4*)(qp + kk * 32);
            float4 c = *(const float4*)(qp + kk * 32 + 4);
            ushort r[8] = {f2bf(a.x), f2bf(a.y), f2bf(a.z), f2bf(a.w),
                           f2bf(c.x), f2bf(c.y), f2bf(c.z), f2bf(c.w)};
            s16x8 raw;
#pragma unroll
            for (int jj = 0; jj < 8; ++jj) raw[jj] = (short)r[jj];
            qf[kk] = __builtin_bit_cast(bf16x8, raw);
        }
    }

    f32x4 o[8];
#pragma unroll
    for (int i = 0; i < 8; ++i) o[i] = (f32x4){0.f, 0.f, 0.f, 0.f};
    float mrow[4] = {-__builtin_inff(), -__builtin_inff(), -__builtin_inff(), -__builtin_inff()};
    float ps[4] = {0.f, 0.f, 0.f, 0.f};

    const int qend_w = qbase + w * 16 + 15;
    const int kv_end = (qbase + QB < SEQ) ? (qbase + QB) : SEQ;

    for (int kv0 = 0; kv0 < kv_end; kv0 += KVB) {
        // ---- stage K rows (coalesced) ----
        {
            int row = tid >> 3, seg = tid & 7;  // 32 rows x 8 segs x 16 shorts
            const ushort* src = ek + (long)(b * SEQ + kv0 + row) * (Hh * Dd) + h * Dd + seg * 16;
            uint4 x0 = *(const uint4*)src;
            uint4 x1 = *(const uint4*)(src + 8);
            *(uint4*)&Kl[row][seg * 16] = x0;
            *(uint4*)&Kl[row][seg * 16 + 8] = x1;
        }
        // ---- stage V transposed ----
        {
            int key = tid & 31, dblk = tid >> 5;  // 32 keys x 8 dblks x 16 d
            const ushort* vsrc = ev + (long)(b * SEQ + kv0 + key) * (Hh * Dd) + h * Dd + dblk * 16;
            uint4 y0 = *(const uint4*)vsrc;
            uint4 y1 = *(const uint4*)(vsrc + 8);
            ushort tmp[16];
            *(uint4*)tmp = y0;
            *(uint4*)(tmp + 8) = y1;
#pragma unroll
            for (int jj = 0; jj < 16; ++jj) Vt[dblk * 16 + jj][key] = tmp[jj];
        }
        __syncthreads();

        if (kv0 <= qend_w) {
            // ---- QK^T: S[16q x 32k] ----
            f32x4 s0 = (f32x4){0.f, 0.f, 0.f, 0.f};
            f32x4 s1 = (f32x4){0.f, 0.f, 0.f, 0.f};
#pragma unroll
            for (int kk = 0; kk < 4; ++kk) {
                bf16x8 k0 = __builtin_bit_cast(bf16x8, *(const s16x8*)&Kl[lr][kk * 32 + qq * 8]);
                bf16x8 k1 = __builtin_bit_cast(bf16x8, *(const s16x8*)&Kl[lr + 16][kk * 32 + qq * 8]);
                s0 = __builtin_amdgcn_mfma_f32_16x16x32_bf16(qf[kk], k0, s0, 0, 0, 0);
                s1 = __builtin_amdgcn_mfma_f32_16x16x32_bf16(qf[kk], k1, s1, 0, 0, 0);
            }
            // ---- online softmax (C layout: col=lr -> key, row=qq*4+r) ----
            const int key0 = kv0 + lr, key1 = kv0 + 16 + lr;
#pragma unroll
            for (int r = 0; r < 4; ++r) {
                const int qpos = qbase + w * 16 + qq * 4 + r;
                float a0 = (key0 <= qpos) ? s0[r] * ATT_SCALE : -__builtin_inff();
                float a1 = (key1 <= qpos) ? s1[r] * ATT_SCALE : -__builtin_inff();
                float t = fmaxf(a0, a1);
                t = fmaxf(t, __shfl_xor(t, 1));
                t = fmaxf(t, __shfl_xor(t, 2));
                t = fmaxf(t, __shfl_xor(t, 4));
                t = fmaxf(t, __shfl_xor(t, 8));
                const float mn = fmaxf(mrow[r], t);
                const float al = __expf(mrow[r] - mn);
                const float p0 = __expf(a0 - mn);  // -inf -> 0
                const float p1 = __expf(a1 - mn);
                ps[r] = ps[r] * al + p0 + p1;
                mrow[r] = mn;
#pragma unroll
                for (int dt = 0; dt < 8; ++dt) o[dt][r] *= al;
                Pl[w][qq * 4 + r][lr] = f2bf(p0);
                Pl[w][qq * 4 + r][16 + lr] = f2bf(p1);
            }
            // ---- PV: O[16q x 128d] += P(16x32) * V(32x128) ----
            bf16x8 pf = __builtin_bit_cast(bf16x8, *(const s16x8*)&Pl[w][lr][qq * 8]);
#pragma unroll
            for (int dt = 0; dt < 8; ++dt) {
                bf16x8 vf = __builtin_bit_cast(bf16x8, *(const s16x8*)&Vt[dt * 16 + lr][qq * 8]);
                o[dt] = __builtin_amdgcn_mfma_f32_16x16x32_bf16(pf, vf, o[dt], 0, 0, 0);
            }
        }
        __syncthreads();
    }

    // ---- epilogue: final l reduce, normalize, store f32 ----
#pragma unroll
    for (int r = 0; r < 4; ++r) {
        float l = ps[r];
        l += __shfl_xor(l, 1);
        l += __shfl_xor(l, 2);
        l += __shfl_xor(l, 4);
        l += __shfl_xor(l, 8);
        const float inv = 1.f / l;
        const int qpos = qbase + w * 16 + qq * 4 + r;
        float* op = out + ((long)(b * SEQ + qpos) * Hh + h) * Dd + lr;
#pragma unroll
        for (int dt = 0; dt < 8; ++dt) op[dt * 16] = o[dt][r] * inv;
    }
}

extern "C" void kernel_launch(void* const* d_in, const int* in_sizes, int n_in,
                              void* d_out, int out_size, void* d_ws, size_t ws_size,
                              hipStream_t stream) {
    const float* q = (const float*)d_in[0];
    const float* k = (const float*)d_in[1];
    const float* v = (const float*)d_in[2];
    const float* k_cache = (const float*)d_in[3];
    const float* v_cache = (const float*)d_in[4];
    const int* slot_mapping = (const int*)d_in[5];
    float* out = (float*)d_out;

    const int T = in_sizes[0] / (Hh * Dd);  // 8192
    const int B = T / SEQ;                  // 4

    ushort* ek = (ushort*)d_ws;
    ushort* ev = ek + (size_t)T * Hh * Dd;

    const long n = (long)T * Hh * Dd;
    const long n8 = n / 8;
    const int cblocks = (int)((n8 + 255) / 256);
    conv_cache<<<cblocks, 256, 0, stream>>>(k_cache, v_cache, ek, ev, n8);
    scatter_kv<<<T, 256, 0, stream>>>(k, v, slot_mapping, ek, ev, T);

    dim3 grid(SEQ / QB, B * Hh);
    attn<<<grid, 256, 0, stream>>>(q, ek, ev, out);
}

// Round 2
// 312.588 us; speedup vs baseline: 1.4839x; 1.4839x over previous
//
#include <hip/hip_runtime.h>

typedef float f32x16 __attribute__((ext_vector_type(16)));
typedef __bf16 bf16x8 __attribute__((ext_vector_type(8)));

#define Hh 16
#define Dd 128
#define SEQ 2048
#define HD 2048                      // Hh*Dd
#define ATT_C 0.12751743f            // (1/sqrt(128)) * log2(e)
#define NEGINF (-__builtin_inff())

__device__ __forceinline__ ushort f2bf(float f) {
    uint u = __builtin_bit_cast(uint, f);
    return (ushort)((u + 0x7FFFu + ((u >> 16) & 1u)) >> 16);
}

__device__ __forceinline__ uint4 pack8(float4 a, float4 b) {
    uint4 u;
    u.x = (uint)f2bf(a.x) | ((uint)f2bf(a.y) << 16);
    u.y = (uint)f2bf(a.z) | ((uint)f2bf(a.w) << 16);
    u.z = (uint)f2bf(b.x) | ((uint)f2bf(b.y) << 16);
    u.w = (uint)f2bf(b.z) | ((uint)f2bf(b.w) << 16);
    return u;
}

__device__ __forceinline__ uint pkbf(float a, float b) {
    return (uint)f2bf(a) | ((uint)f2bf(b) << 16);
}

__device__ __forceinline__ f32x16 zero16() {
    f32x16 v;
#pragma unroll
    for (int i = 0; i < 16; ++i) v[i] = 0.f;
    return v;
}

// build PV A-fragment word set from packed P pairs via half-swap
// inputs: a01=pk(r0,r1) a23=pk(r2,r3) a45=pk(r4,r5) a67=pk(r6,r7) (or r8..15)
__device__ __forceinline__ bf16x8 mkfrag(uint a01, uint a23, uint a45, uint a67, int hi) {
    uint s01 = __shfl_xor(a01, 32), s23 = __shfl_xor(a23, 32);
    uint s45 = __shfl_xor(a45, 32), s67 = __shfl_xor(a67, 32);
    uint4 u;
    u.x = hi ? s45 : a01;   // keys +0,+1   (hi: +8,+9)
    u.y = hi ? s67 : a23;   // keys +2,+3   (hi: +10,+11)
    u.z = hi ? a45 : s01;   // keys +4,+5   (hi: +12,+13)
    u.w = hi ? a67 : s23;   // keys +6,+7   (hi: +14,+15)
    return __builtin_bit_cast(bf16x8, u);
}

// ---- Kernel 1: k_cache[:T] f32 -> ek bf16 row-major ----
__global__ void convk(const float* __restrict__ kc, ushort* __restrict__ ek, long n8) {
    long i = (long)blockIdx.x * blockDim.x + threadIdx.x;
    if (i >= n8) return;
    float4 a = *(const float4*)(kc + i * 8);
    float4 b = *(const float4*)(kc + i * 8 + 4);
    *(uint4*)(ek + i * 8) = pack8(a, b);
}

// ---- Kernel 2: v_cache[:T] f32 -> evt bf16 transposed [bh][d][tok] ----
__global__ void convvt(const float* __restrict__ vc, ushort* __restrict__ evt) {
    __shared__ ushort Lt[64][72];  // [d][tok]
    const int tid = threadIdx.x;
    const int t0 = blockIdx.x * 64, d0 = blockIdx.y * 64, bh = blockIdx.z;
    const int b = bh >> 4, h = bh & 15;
    const int d = tid & 63, rg = tid >> 6;  // rg 0..3
#pragma unroll
    for (int rd = 0; rd < 4; ++rd) {
        ushort t0w, t1w, t2w, t3w;
        const long base = (long)(b * SEQ + t0 + rd * 16 + rg * 4) * HD + h * Dd + d0 + d;
        t0w = f2bf(vc[base]);
        t1w = f2bf(vc[base + HD]);
        t2w = f2bf(vc[base + 2 * HD]);
        t3w = f2bf(vc[base + 3 * HD]);
        uint2 u;
        u.x = (uint)t0w | ((uint)t1w << 16);
        u.y = (uint)t2w | ((uint)t3w << 16);
        *(uint2*)&Lt[d][rd * 16 + rg * 4] = u;
    }
    __syncthreads();
#pragma unroll
    for (int rd = 0; rd < 2; ++rd) {
        int idx = rd * 256 + tid, dd = idx >> 3, s = idx & 7;
        *(uint4*)(evt + ((long)bh * Dd + d0 + dd) * SEQ + t0 + s * 8) = *(const uint4*)&Lt[dd][s * 8];
    }
}

// ---- Kernel 3: scatter token k/v into ek (row-major) and evt (transposed) ----
__global__ void scat(const float* __restrict__ k, const float* __restrict__ v,
                     const int* __restrict__ slots, ushort* __restrict__ ek,
                     ushort* __restrict__ evt, int T) {
    __shared__ int sl[64];
    __shared__ ushort Lt[128][72];  // V tile [d][tok]
    const int tid = threadIdx.x;
    const int g0 = blockIdx.x * 64;
    const int h = blockIdx.y;
    if (tid < 64) sl[tid] = slots[g0 + tid];
    // stage V transposed (scalar reads, coalesced by d)
    const int d = tid & 127, half = tid >> 7;
#pragma unroll
    for (int rd = 0; rd < 8; ++rd) {
        const long base = (long)(g0 + rd * 8 + half * 4) * HD + h * Dd + d;
        ushort w0 = f2bf(v[base]);
        ushort w1 = f2bf(v[base + HD]);
        ushort w2 = f2bf(v[base + 2 * HD]);
        ushort w3 = f2bf(v[base + 3 * HD]);
        uint2 u;
        u.x = (uint)w0 | ((uint)w1 << 16);
        u.y = (uint)w2 | ((uint)w3 << 16);
        *(uint2*)&Lt[d][rd * 8 + half * 4] = u;
    }
    __syncthreads();
    // K scatter: row-major vectorized
#pragma unroll
    for (int rd = 0; rd < 4; ++rd) {
        int idx = rd * 256 + tid, r = idx >> 4, sg = idx & 15;
        int s = sl[r];
        if (s >= 0 && s < T) {
            const float* kp = k + (long)(g0 + r) * HD + h * Dd + sg * 8;
            float4 A = *(const float4*)kp;
            float4 B = *(const float4*)(kp + 4);
            *(uint4*)(ek + (long)s * HD + h * Dd + sg * 8) = pack8(A, B);
        }
    }
    // V scatter: per-element columns into evt
#pragma unroll
    for (int rd = 0; rd < 4; ++rd) {
        int idx = rd * 256 + tid, dd = idx >> 3, sg = idx & 7;
        union { uint4 u; ushort us[8]; } t;
        t.u = *(const uint4*)&Lt[dd][sg * 8];
#pragma unroll
        for (int j = 0; j < 8; ++j) {
            int s = sl[sg * 8 + j];
            if (s >= 0 && s < T)
                evt[((long)((s >> 11) * Hh + h) * Dd + dd) * SEQ + (s & (SEQ - 1))] = t.us[j];
        }
    }
}

// ---- Kernel 4: causal flash attention, 32x32x16 swapped-QK, in-register softmax ----
__global__ __launch_bounds__(512, 2) void attn32(const float* __restrict__ q,
                                                 const ushort* __restrict__ ek,
                                                 const ushort* __restrict__ evt,
                                                 float* __restrict__ out) {
    __shared__ ushort Kl[64][136];   // K rows [key][d], +8 pad
    __shared__ ushort Vt[128][72];   // V transposed [d][key], +8 pad

    const int tid = threadIdx.x;
    const int w = tid >> 6, lane = tid & 63;
    const int l31 = lane & 31, hi = lane >> 5;
    const int bh = blockIdx.y, b = bh >> 4, h = bh & 15;
    // balanced causal pairing: 0,7,1,6,2,5,3,4
    const int px = blockIdx.x;
    const int xt = (px & 1) ? (7 - (px >> 1)) : (px >> 1);
    const int qbase = xt * 256;
    const int qtb = qbase + w * 32;      // wave's q-tile base
    const int qpos = qtb + l31;          // this lane's q row

    // Q B-fragments: lane holds Q[q=l31][d = kk*16 + hi*8 + j]
    bf16x8 qf[8];
    {
        const float* qp = q + ((long)(b * SEQ + qtb + l31) * Hh + h) * Dd + hi * 8;
#pragma unroll
        for (int kk = 0; kk < 8; ++kk) {
            float4 A = *(const float4*)(qp + kk * 16);
            float4 B = *(const float4*)(qp + kk * 16 + 4);
            union { uint4 u; bf16x8 v; } cv;
            cv.u = pack8(A, B);
            qf[kk] = cv.v;
        }
    }

    f32x16 o[4];
#pragma unroll
    for (int nt = 0; nt < 4; ++nt) o[nt] = zero16();
    float m = NEGINF, lsum = 0.f;

    const int kv_end = qbase + 256;
    for (int kv0 = 0; kv0 < kv_end; kv0 += 64) {
        // ---- stage K (64 rows x 128 d) ----
#pragma unroll
        for (int rd = 0; rd < 2; ++rd) {
            int idx = rd * 512 + tid, row = idx >> 4, seg = idx & 15;
            *(uint4*)&Kl[row][seg * 8] =
                *(const uint4*)(ek + ((long)(b * SEQ + kv0 + row) * Hh + h) * Dd + seg * 8);
        }
        // ---- stage Vt (128 d x 64 keys) from pre-transposed evt ----
#pragma unroll
        for (int rd = 0; rd < 2; ++rd) {
            int idx = rd * 512 + tid, dd = idx >> 3, seg = idx & 7;
            *(uint4*)&Vt[dd][seg * 8] =
                *(const uint4*)(evt + ((long)bh * Dd + dd) * SEQ + kv0 + seg * 8);
        }
        __syncthreads();

        if (kv0 <= qtb + 31) {  // wave has at least one unmasked key
            // ---- QK^T swapped: C[key][q], two 32-key chunks ----
            f32x16 s0 = zero16(), s1 = zero16();
#pragma unroll
            for (int kk = 0; kk < 8; ++kk) {
                bf16x8 kf0 = *(const bf16x8*)&Kl[l31][kk * 16 + hi * 8];
                bf16x8 kf1 = *(const bf16x8*)&Kl[32 + l31][kk * 16 + hi * 8];
                s0 = __builtin_amdgcn_mfma_f32_32x32x16_bf16(kf0, qf[kk], s0, 0, 0, 0);
                s1 = __builtin_amdgcn_mfma_f32_32x32x16_bf16(kf1, qf[kk], s1, 0, 0, 0);
            }
            // ---- scale + causal mask + tile max (z = S*scale*log2e) ----
            float mt = NEGINF;
            const bool needmask = (kv0 + 63 > qtb);
            if (needmask) {
#pragma unroll
                for (int r = 0; r < 16; ++r) {
                    const int kr = kv0 + ((r & 3) + 8 * (r >> 2) + 4 * hi);
                    float a0 = (kr <= qpos) ? s0[r] * ATT_C : NEGINF;
                    float a1 = (kr + 32 <= qpos) ? s1[r] * ATT_C : NEGINF;
                    s0[r] = a0; s1[r] = a1;
                    mt = fmaxf(mt, fmaxf(a0, a1));
                }
            } else {
#pragma unroll
                for (int r = 0; r < 16; ++r) {
                    s0[r] *= ATT_C; s1[r] *= ATT_C;
                    mt = fmaxf(mt, fmaxf(s0[r], s1[r]));
                }
            }
            mt = fmaxf(mt, __shfl_xor(mt, 32));
            // ---- defer-max online rescale (THR=8) ----
            if (!__all(mt <= m + 8.f)) {
                const float mn = fmaxf(m, mt);
                const float al = exp2f(m - mn);
                m = mn;
                lsum *= al;
#pragma unroll
                for (int r = 0; r < 16; ++r) {
                    const float alr = __shfl(al, (r & 3) + 8 * (r >> 2) + 4 * hi);
                    o[0][r] *= alr; o[1][r] *= alr; o[2][r] *= alr; o[3][r] *= alr;
                }
            }
            // ---- P = exp2(z - m), row sum ----
            float psum = 0.f;
#pragma unroll
            for (int r = 0; r < 16; ++r) {
                s0[r] = exp2f(s0[r] - m);
                s1[r] = exp2f(s1[r] - m);
                psum += s0[r] + s1[r];
            }
            lsum += psum;
            // ---- pack P -> bf16 A-fragments (half-swap) ----
            uint c00 = pkbf(s0[0], s0[1]),   c01 = pkbf(s0[2], s0[3]);
            uint c02 = pkbf(s0[4], s0[5]),   c03 = pkbf(s0[6], s0[7]);
            uint c04 = pkbf(s0[8], s0[9]),   c05 = pkbf(s0[10], s0[11]);
            uint c06 = pkbf(s0[12], s0[13]), c07 = pkbf(s0[14], s0[15]);
            uint c10 = pkbf(s1[0], s1[1]),   c11 = pkbf(s1[2], s1[3]);
            uint c12 = pkbf(s1[4], s1[5]),   c13 = pkbf(s1[6], s1[7]);
            uint c14 = pkbf(s1[8], s1[9]),   c15 = pkbf(s1[10], s1[11]);
            uint c16 = pkbf(s1[12], s1[13]), c17 = pkbf(s1[14], s1[15]);
            bf16x8 pa00 = mkfrag(c00, c01, c02, c03, hi);  // keys kv0+ 0..15
            bf16x8 pa01 = mkfrag(c04, c05, c06, c07, hi);  // keys kv0+16..31
            bf16x8 pa10 = mkfrag(c10, c11, c12, c13, hi);  // keys kv0+32..47
            bf16x8 pa11 = mkfrag(c14, c15, c16, c17, hi);  // keys kv0+48..63
            // ---- PV: O[q][d] += P * V ----
#pragma unroll
            for (int nt = 0; nt < 4; ++nt) {
                const int dr = nt * 32 + l31;
                o[nt] = __builtin_amdgcn_mfma_f32_32x32x16_bf16(pa00, *(const bf16x8*)&Vt[dr][0  + hi * 8], o[nt], 0, 0, 0);
                o[nt] = __builtin_amdgcn_mfma_f32_32x32x16_bf16(pa01, *(const bf16x8*)&Vt[dr][16 + hi * 8], o[nt], 0, 0, 0);
                o[nt] = __builtin_amdgcn_mfma_f32_32x32x16_bf16(pa10, *(const bf16x8*)&Vt[dr][32 + hi * 8], o[nt], 0, 0, 0);
                o[nt] = __builtin_amdgcn_mfma_f32_32x32x16_bf16(pa11, *(const bf16x8*)&Vt[dr][48 + hi * 8], o[nt], 0, 0, 0);
            }
        }
        __syncthreads();
    }

    // ---- epilogue: merge halves of l, normalize, store ----
    const float lt = lsum + __shfl_xor(lsum, 32);
    const float inv = 1.f / lt;
#pragma unroll
    for (int r = 0; r < 16; ++r) {
        const int qr = (r & 3) + 8 * (r >> 2) + 4 * hi;
        const float ivr = __shfl(inv, qr);
        float* op = out + ((long)(b * SEQ + qtb + qr) * Hh + h) * Dd + l31;
        op[0]  = o[0][r] * ivr;
        op[32] = o[1][r] * ivr;
        op[64] = o[2][r] * ivr;
        op[96] = o[3][r] * ivr;
    }
}

extern "C" void kernel_launch(void* const* d_in, const int* in_sizes, int n_in,
                              void* d_out, int out_size, void* d_ws, size_t ws_size,
                              hipStream_t stream) {
    const float* q = (const float*)d_in[0];
    const float* k = (const float*)d_in[1];
    const float* v = (const float*)d_in[2];
    const float* k_cache = (const float*)d_in[3];
    const float* v_cache = (const float*)d_in[4];
    const int* slot_mapping = (const int*)d_in[5];
    float* out = (float*)d_out;

    const int T = in_sizes[0] / HD;  // 8192
    const int B = T / SEQ;           // 4

    ushort* ek = (ushort*)d_ws;                       // [T][H*D] bf16
    ushort* evt = ek + (size_t)T * HD;                // [B*H][D][SEQ] bf16

    const long n8 = (long)T * HD / 8;
    convk<<<(int)((n8 + 255) / 256), 256, 0, stream>>>(k_cache, ek, n8);
    convvt<<<dim3(SEQ / 64, Dd / 64, B * Hh), 256, 0, stream>>>(v_cache, evt);
    scat<<<dim3(T / 64, Hh), 256, 0, stream>>>(k, v, slot_mapping, ek, evt, T);
    attn32<<<dim3(SEQ / 256, B * Hh), 512, 0, stream>>>(q, ek, evt, out);
}

// Round 3
// 270.288 us; speedup vs baseline: 1.7162x; 1.1565x over previous
//
#include <hip/hip_runtime.h>

typedef float f32x16 __attribute__((ext_vector_type(16)));
typedef __bf16 bf16x8 __attribute__((ext_vector_type(8)));

#define Hh 16
#define Dd 128
#define SEQ 2048
#define HD 2048                      // Hh*Dd
#define ATT_C 0.12751743f            // (1/sqrt(128)) * log2(e)
#define NEGINF (-__builtin_inff())

__device__ __forceinline__ ushort f2bf(float f) {
    uint u = __builtin_bit_cast(uint, f);
    return (ushort)((u + 0x7FFFu + ((u >> 16) & 1u)) >> 16);
}

__device__ __forceinline__ uint4 pack8(float4 a, float4 b) {
    uint4 u;
    u.x = (uint)f2bf(a.x) | ((uint)f2bf(a.y) << 16);
    u.y = (uint)f2bf(a.z) | ((uint)f2bf(a.w) << 16);
    u.z = (uint)f2bf(b.x) | ((uint)f2bf(b.y) << 16);
    u.w = (uint)f2bf(b.z) | ((uint)f2bf(b.w) << 16);
    return u;
}

__device__ __forceinline__ uint pkbf(float a, float b) {
    return (uint)f2bf(a) | ((uint)f2bf(b) << 16);
}

__device__ __forceinline__ f32x16 zero16() {
    f32x16 v;
#pragma unroll
    for (int i = 0; i < 16; ++i) v[i] = 0.f;
    return v;
}

// build PV A-fragment from packed P pairs via half-swap (verified R2)
__device__ __forceinline__ bf16x8 mkfrag(uint a01, uint a23, uint a45, uint a67, int hi) {
    uint s01 = __shfl_xor(a01, 32), s23 = __shfl_xor(a23, 32);
    uint s45 = __shfl_xor(a45, 32), s67 = __shfl_xor(a67, 32);
    uint4 u;
    u.x = hi ? s45 : a01;
    u.y = hi ? s67 : a23;
    u.z = hi ? a45 : s01;
    u.w = hi ? a67 : s23;
    return __builtin_bit_cast(bf16x8, u);
}

// ---- inverse slot map ----
__global__ void initinv(int* __restrict__ inv, int T) {
    int i = blockIdx.x * 256 + threadIdx.x;
    if (i < T) inv[i] = -1;
}
__global__ void buildinv(const int* __restrict__ slots, int* __restrict__ inv, int T) {
    int t = blockIdx.x * 256 + threadIdx.x;
    if (t < T) { int s = slots[t]; if (s >= 0 && s < T) inv[s] = t; }
}

// ---- fused effective-KV materialization: ek row-major bf16, evt transposed bf16 ----
__global__ void fusekv(const float* __restrict__ k, const float* __restrict__ v,
                       const float* __restrict__ kc, const float* __restrict__ vc,
                       const int* __restrict__ inv, ushort* __restrict__ ek,
                       ushort* __restrict__ evt) {
    __shared__ int sv[64];
    __shared__ ushort Lt[128][72];
    const int tid = threadIdx.x;
    const int r0 = blockIdx.x * 64, h = blockIdx.y;
    const int b = r0 >> 11, tok0 = r0 & (SEQ - 1);
    if (tid < 64) sv[tid] = inv[r0 + tid];
    __syncthreads();
    // K rows: pick source per row, write ek row-major
#pragma unroll
    for (int i = 0; i < 4; ++i) {
        int idx = i * 256 + tid, r = idx >> 4, sg = idx & 15;
        int s = sv[r];
        const float* src = (s >= 0 ? k + (long)s * HD : kc + (long)(r0 + r) * HD) + h * Dd + sg * 8;
        float4 A = *(const float4*)src;
        float4 Bv = *(const float4*)(src + 4);
        *(uint4*)(ek + (long)(r0 + r) * HD + h * Dd + sg * 8) = pack8(A, Bv);
    }
    // V: coalesced-by-d reads, LDS transpose
    const int d = tid & 127, half = tid >> 7;
#pragma unroll
    for (int i = 0; i < 8; ++i) {
        const int t = i * 8 + half * 4;
        ushort wv[4];
#pragma unroll
        for (int jj = 0; jj < 4; ++jj) {
            int s = sv[t + jj];
            const float* sp = (s >= 0 ? v + (long)s * HD : vc + (long)(r0 + t + jj) * HD) + h * Dd + d;
            wv[jj] = f2bf(*sp);
        }
        uint2 u;
        u.x = (uint)wv[0] | ((uint)wv[1] << 16);
        u.y = (uint)wv[2] | ((uint)wv[3] << 16);
        *(uint2*)&Lt[d][t] = u;
    }
    __syncthreads();
#pragma unroll
    for (int i = 0; i < 4; ++i) {
        int idx = i * 256 + tid, dd = idx >> 3, sg = idx & 7;
        *(uint4*)(evt + ((long)(b * Hh + h) * Dd + dd) * SEQ + tok0 + sg * 8) = *(const uint4*)&Lt[dd][sg * 8];
    }
}

// ---- causal flash attention: 4 waves, qtile pair {j,15-j}, LDS dbuf, async stage ----
__global__ __launch_bounds__(256, 2) void attn32(const float* __restrict__ q,
                                                 const ushort* __restrict__ ek,
                                                 const ushort* __restrict__ evt,
                                                 float* __restrict__ out) {
    __shared__ ushort Kl[2][64][136];
    __shared__ ushort Vt[2][128][72];

    const int tid = threadIdx.x;
    const int w = tid >> 6, lane = tid & 63;
    const int l31 = lane & 31, hi = lane >> 5;
    const int g = blockIdx.x;
    const int bh = g & 63, j = g >> 6;          // xcd ~ bh%8 -> per-XCD K/V L2 locality
    const int b = bh >> 4, h = bh & 15;
    const int n1 = 2 * (j + 1), ns = 34;        // steps: 2(j+1) + 2(16-j) = 34 for all blocks

    uint4 kst[4], vst[4];
    bf16x8 qf[8];

    auto issue = [&](int kv0) {
#pragma unroll
        for (int i = 0; i < 4; ++i) {
            int idx = i * 256 + tid, row = idx >> 4, sg = idx & 15;
            kst[i] = *(const uint4*)(ek + (long)(b * SEQ + kv0 + row) * HD + h * Dd + sg * 8);
        }
#pragma unroll
        for (int i = 0; i < 4; ++i) {
            int idx = i * 256 + tid, dd = idx >> 3, sg = idx & 7;
            vst[i] = *(const uint4*)(evt + ((long)bh * Dd + dd) * SEQ + kv0 + sg * 8);
        }
    };
    auto writebuf = [&](int bufi) {
#pragma unroll
        for (int i = 0; i < 4; ++i) {
            int idx = i * 256 + tid, row = idx >> 4, sg = idx & 15;
            *(uint4*)&Kl[bufi][row][sg * 8] = kst[i];
        }
#pragma unroll
        for (int i = 0; i < 4; ++i) {
            int idx = i * 256 + tid, dd = idx >> 3, sg = idx & 7;
            *(uint4*)&Vt[bufi][dd][sg * 8] = vst[i];
        }
    };
    auto loadq = [&](int qt) {
        const int qrow = qt * 128 + w * 32 + l31;
        const float* qp = q + ((long)(b * SEQ + qrow) * Hh + h) * Dd + hi * 8;
#pragma unroll
        for (int kk = 0; kk < 8; ++kk) {
            float4 A = *(const float4*)(qp + kk * 16);
            float4 Bv = *(const float4*)(qp + kk * 16 + 4);
            union { uint4 u; bf16x8 v; } cv;
            cv.u = pack8(A, Bv);
            qf[kk] = cv.v;
        }
    };

    f32x16 o[4];
#pragma unroll
    for (int nt = 0; nt < 4; ++nt) o[nt] = zero16();
    float m = NEGINF, lsum = 0.f;

    issue(0);
    loadq(j);
    writebuf(0);
    __syncthreads();

    int cur = 0;
    int qt = j;
    int qtb = qt * 128 + w * 32;

    for (int s = 0; s < ns; ++s) {
        const int kv0 = (s < n1 ? s : s - n1) * 64;
        if (s + 1 < ns) {
            const int nkv0 = (s + 1 < n1 ? s + 1 : s + 1 - n1) * 64;
            issue(nkv0);
        }
        if (s == n1) {  // switch to second qtile
            qt = 15 - j;
            qtb = qt * 128 + w * 32;
            loadq(qt);
        }
        const int qpos = qtb + l31;

        if (kv0 <= qtb + 31) {
            // ---- QK^T swapped: C[key][q] ----
            f32x16 s0 = zero16(), s1 = zero16();
            __builtin_amdgcn_s_setprio(1);
#pragma unroll
            for (int kk = 0; kk < 8; ++kk) {
                bf16x8 kf0 = *(const bf16x8*)&Kl[cur][l31][kk * 16 + hi * 8];
                bf16x8 kf1 = *(const bf16x8*)&Kl[cur][32 + l31][kk * 16 + hi * 8];
                s0 = __builtin_amdgcn_mfma_f32_32x32x16_bf16(kf0, qf[kk], s0, 0, 0, 0);
                s1 = __builtin_amdgcn_mfma_f32_32x32x16_bf16(kf1, qf[kk], s1, 0, 0, 0);
            }
            __builtin_amdgcn_s_setprio(0);
            // ---- scale + causal mask + tile max ----
            float mt = NEGINF;
            const bool needmask = (kv0 + 63 > qtb);
            if (needmask) {
#pragma unroll
                for (int r = 0; r < 16; ++r) {
                    const int kr = kv0 + ((r & 3) + 8 * (r >> 2) + 4 * hi);
                    float a0 = (kr <= qpos) ? s0[r] * ATT_C : NEGINF;
                    float a1 = (kr + 32 <= qpos) ? s1[r] * ATT_C : NEGINF;
                    s0[r] = a0; s1[r] = a1;
                    mt = fmaxf(mt, fmaxf(a0, a1));
                }
            } else {
#pragma unroll
                for (int r = 0; r < 16; ++r) {
                    s0[r] *= ATT_C; s1[r] *= ATT_C;
                    mt = fmaxf(mt, fmaxf(s0[r], s1[r]));
                }
            }
            mt = fmaxf(mt, __shfl_xor(mt, 32));
            // ---- defer-max rescale (THR=8 in log2 domain) ----
            if (!__all(mt <= m + 8.f)) {
                const float mn = fmaxf(m, mt);
                const float al = exp2f(m - mn);
                m = mn;
                lsum *= al;
#pragma unroll
                for (int r = 0; r < 16; ++r) {
                    const float alr = __shfl(al, (r & 3) + 8 * (r >> 2) + 4 * hi);
                    o[0][r] *= alr; o[1][r] *= alr; o[2][r] *= alr; o[3][r] *= alr;
                }
            }
            // ---- P = exp2(z - m) ----
            float psum = 0.f;
#pragma unroll
            for (int r = 0; r < 16; ++r) {
                s0[r] = exp2f(s0[r] - m);
                s1[r] = exp2f(s1[r] - m);
                psum += s0[r] + s1[r];
            }
            lsum += psum;
            // ---- pack P -> A-fragments ----
            uint c00 = pkbf(s0[0], s0[1]),   c01 = pkbf(s0[2], s0[3]);
            uint c02 = pkbf(s0[4], s0[5]),   c03 = pkbf(s0[6], s0[7]);
            uint c04 = pkbf(s0[8], s0[9]),   c05 = pkbf(s0[10], s0[11]);
            uint c06 = pkbf(s0[12], s0[13]), c07 = pkbf(s0[14], s0[15]);
            uint c10 = pkbf(s1[0], s1[1]),   c11 = pkbf(s1[2], s1[3]);
            uint c12 = pkbf(s1[4], s1[5]),   c13 = pkbf(s1[6], s1[7]);
            uint c14 = pkbf(s1[8], s1[9]),   c15 = pkbf(s1[10], s1[11]);
            uint c16 = pkbf(s1[12], s1[13]), c17 = pkbf(s1[14], s1[15]);
            bf16x8 pa00 = mkfrag(c00, c01, c02, c03, hi);
            bf16x8 pa01 = mkfrag(c04, c05, c06, c07, hi);
            bf16x8 pa10 = mkfrag(c10, c11, c12, c13, hi);
            bf16x8 pa11 = mkfrag(c14, c15, c16, c17, hi);
            // ---- PV ----
            __builtin_amdgcn_s_setprio(1);
#pragma unroll
            for (int nt = 0; nt < 4; ++nt) {
                const int dr = nt * 32 + l31;
                o[nt] = __builtin_amdgcn_mfma_f32_32x32x16_bf16(pa00, *(const bf16x8*)&Vt[cur][dr][0  + hi * 8], o[nt], 0, 0, 0);
                o[nt] = __builtin_amdgcn_mfma_f32_32x32x16_bf16(pa01, *(const bf16x8*)&Vt[cur][dr][16 + hi * 8], o[nt], 0, 0, 0);
                o[nt] = __builtin_amdgcn_mfma_f32_32x32x16_bf16(pa10, *(const bf16x8*)&Vt[cur][dr][32 + hi * 8], o[nt], 0, 0, 0);
                o[nt] = __builtin_amdgcn_mfma_f32_32x32x16_bf16(pa11, *(const bf16x8*)&Vt[cur][dr][48 + hi * 8], o[nt], 0, 0, 0);
            }
            __builtin_amdgcn_s_setprio(0);
        }

        if (s == n1 - 1 || s == ns - 1) {
            // ---- epilogue for this qtile ----
            const float lt = lsum + __shfl_xor(lsum, 32);
            const float inv_ = 1.f / lt;
#pragma unroll
            for (int r = 0; r < 16; ++r) {
                const int qr = (r & 3) + 8 * (r >> 2) + 4 * hi;
                const float ivr = __shfl(inv_, qr);
                float* op = out + ((long)(b * SEQ + qtb + qr) * Hh + h) * Dd + l31;
                op[0]  = o[0][r] * ivr;
                op[32] = o[1][r] * ivr;
                op[64] = o[2][r] * ivr;
                op[96] = o[3][r] * ivr;
            }
#pragma unroll
            for (int nt = 0; nt < 4; ++nt) o[nt] = zero16();
            m = NEGINF; lsum = 0.f;
        }

        if (s + 1 < ns) writebuf(cur ^ 1);
        __syncthreads();
        cur ^= 1;
    }
}

extern "C" void kernel_launch(void* const* d_in, const int* in_sizes, int n_in,
                              void* d_out, int out_size, void* d_ws, size_t ws_size,
                              hipStream_t stream) {
    const float* q = (const float*)d_in[0];
    const float* k = (const float*)d_in[1];
    const float* v = (const float*)d_in[2];
    const float* k_cache = (const float*)d_in[3];
    const float* v_cache = (const float*)d_in[4];
    const int* slot_mapping = (const int*)d_in[5];
    float* out = (float*)d_out;

    const int T = in_sizes[0] / HD;  // 8192
    (void)n_in; (void)out_size; (void)ws_size;

    ushort* ek = (ushort*)d_ws;                         // [T][HD] bf16       (32 MB)
    ushort* evt = ek + (size_t)T * HD;                  // [B*H][D][SEQ] bf16 (32 MB)
    int* inv = (int*)(evt + (size_t)T * HD);            // [T] int            (32 KB)

    initinv<<<T / 256, 256, 0, stream>>>(inv, T);
    buildinv<<<T / 256, 256, 0, stream>>>(slot_mapping, inv, T);
    fusekv<<<dim3(T / 64, Hh), 256, 0, stream>>>(k, v, k_cache, v_cache, inv, ek, evt);
    attn32<<<dim3(512), 256, 0, stream>>>(q, ek, evt, out);
}

// Round 4
// 159.125 us; speedup vs baseline: 2.9151x; 1.6986x over previous
//
#include <hip/hip_runtime.h>

typedef float f32x16 __attribute__((ext_vector_type(16)));
typedef __bf16 bf16x8 __attribute__((ext_vector_type(8)));
typedef unsigned int uint2v __attribute__((ext_vector_type(2)));

#define Hh 16
#define Dd 128
#define SEQ 2048
#define HD 2048                      // Hh*Dd
#define ATT_C 0.12751743f            // (1/sqrt(128)) * log2(e)
#define NEGINF (-__builtin_inff())

__device__ __forceinline__ ushort f2bf(float f) {
    uint u = __builtin_bit_cast(uint, f);
    return (ushort)((u + 0x7FFFu + ((u >> 16) & 1u)) >> 16);
}

__device__ __forceinline__ uint4 pack8(float4 a, float4 b) {
    uint4 u;
    u.x = (uint)f2bf(a.x) | ((uint)f2bf(a.y) << 16);
    u.y = (uint)f2bf(a.z) | ((uint)f2bf(a.w) << 16);
    u.z = (uint)f2bf(b.x) | ((uint)f2bf(b.y) << 16);
    u.w = (uint)f2bf(b.z) | ((uint)f2bf(b.w) << 16);
    return u;
}

__device__ __forceinline__ uint pkbf(float a, float b) {
    return (uint)f2bf(a) | ((uint)f2bf(b) << 16);
}

__device__ __forceinline__ f32x16 zero16() {
    f32x16 v;
#pragma unroll
    for (int i = 0; i < 16; ++i) v[i] = 0.f;
    return v;
}

// async global->LDS, 16 B per lane (dest must be tid-linear: base + lane*16)
__device__ __forceinline__ void gll16(const void* g, void* l) {
    __builtin_amdgcn_global_load_lds(
        (const __attribute__((address_space(1))) unsigned int*)g,
        (__attribute__((address_space(3))) unsigned int*)l, 16, 0, 0);
}

// PV A-fragment assembly via permlane32_swap (T12); verified mapping from R2
__device__ __forceinline__ bf16x8 mkfrag(uint a01, uint a23, uint a45, uint a67, int hi) {
    uint4 u;
#if __has_builtin(__builtin_amdgcn_permlane32_swap)
    uint2v xz = __builtin_amdgcn_permlane32_swap(a01, a45, false, false);
    uint2v yw = __builtin_amdgcn_permlane32_swap(a23, a67, false, false);
    u.x = xz[0]; u.y = yw[0]; u.z = xz[1]; u.w = yw[1];
    (void)hi;
#else
    uint s01 = __shfl_xor(a01, 32), s23 = __shfl_xor(a23, 32);
    uint s45 = __shfl_xor(a45, 32), s67 = __shfl_xor(a67, 32);
    u.x = hi ? s45 : a01;
    u.y = hi ? s67 : a23;
    u.z = hi ? a45 : s01;
    u.w = hi ? a67 : s23;
#endif
    return __builtin_bit_cast(bf16x8, u);
}

// ---- inverse slot map ----
__global__ void initinv(int* __restrict__ inv, int T) {
    int i = blockIdx.x * 256 + threadIdx.x;
    if (i < T) inv[i] = -1;
}
__global__ void buildinv(const int* __restrict__ slots, int* __restrict__ inv, int T) {
    int t = blockIdx.x * 256 + threadIdx.x;
    if (t < T) { int s = slots[t]; if (s >= 0 && s < T) inv[s] = t; }
}

// ---- fused effective-KV materialization into FRAGMENT-MAJOR 16KB tiles ----
// K tile chunk c = (half*16 + j)*32 + l : 16B = K[key=half*32+l][d=j*8..j*8+7]
// V tile chunk c = (nt*8 + ch)*32 + l   : 16B = V[key=ch*8..+7][d=nt*32+l]
__global__ void fusekv(const float* __restrict__ k, const float* __restrict__ v,
                       const float* __restrict__ kc, const float* __restrict__ vc,
                       const int* __restrict__ inv, ushort* __restrict__ ek,
                       ushort* __restrict__ evt) {
    __shared__ int sv[64];
    __shared__ ushort Ks[64][136];
    __shared__ ushort Lt[128][72];
    const int tid = threadIdx.x;
    const int r0 = blockIdx.x * 64, h = blockIdx.y;
    const int b = r0 >> 11, tok0 = r0 & (SEQ - 1);
    const long tb = ((long)(b * Hh + h) * 32 + (tok0 >> 6)) * 8192;  // short offset of tile
    if (tid < 64) sv[tid] = inv[r0 + tid];
    __syncthreads();
    // K rows: coalesced reads -> LDS row-major
#pragma unroll
    for (int i = 0; i < 4; ++i) {
        int idx = i * 256 + tid, r = idx >> 4, sg = idx & 15;
        int s = sv[r];
        const float* src = (s >= 0 ? k + (long)s * HD : kc + (long)(r0 + r) * HD) + h * Dd + sg * 8;
        float4 A = *(const float4*)src;
        float4 Bv = *(const float4*)(src + 4);
        *(uint4*)&Ks[r][sg * 8] = pack8(A, Bv);
    }
    // V: coalesced-by-d reads -> LDS transposed [d][tok]
    const int d = tid & 127, hf2 = tid >> 7;
#pragma unroll
    for (int i = 0; i < 8; ++i) {
        const int t = i * 8 + hf2 * 4;
        ushort wv[4];
#pragma unroll
        for (int jj = 0; jj < 4; ++jj) {
            int s = sv[t + jj];
            const float* sp = (s >= 0 ? v + (long)s * HD : vc + (long)(r0 + t + jj) * HD) + h * Dd + d;
            wv[jj] = f2bf(*sp);
        }
        uint2 u;
        u.x = (uint)wv[0] | ((uint)wv[1] << 16);
        u.y = (uint)wv[2] | ((uint)wv[3] << 16);
        *(uint2*)&Lt[d][t] = u;
    }
    __syncthreads();
    // emit fragment-major tiles, fully coalesced 16B writes
#pragma unroll
    for (int i = 0; i < 4; ++i) {
        int c = i * 256 + tid, l = c & 31, j = (c >> 5) & 15, hf = c >> 9;
        *(uint4*)(ek + tb + (long)c * 8) = *(const uint4*)&Ks[hf * 32 + l][j * 8];
    }
#pragma unroll
    for (int i = 0; i < 4; ++i) {
        int c = i * 256 + tid, l = c & 31, ch = (c >> 5) & 7, nt = c >> 8;
        *(uint4*)(evt + tb + (long)c * 8) = *(const uint4*)&Lt[nt * 32 + l][ch * 8];
    }
}

// ---- causal flash attention: gload_lds double-buffer, fragment-major tiles ----
__global__ __launch_bounds__(256, 2) void attn32(const float* __restrict__ q,
                                                 const ushort* __restrict__ ek,
                                                 const ushort* __restrict__ evt,
                                                 float* __restrict__ out) {
    __shared__ ushort KV[2][16384];  // [buf][ K tile 8192 | V tile 8192 ] shorts

    const int tid = threadIdx.x;
    const int w = tid >> 6, lane = tid & 63;
    const int l31 = lane & 31, hi = lane >> 5;
    const int g = blockIdx.x;
    const int bh = g & 63, j = g >> 6;   // all 8 j-blocks of a bh land on XCD bh%8
    const int b = bh >> 4, h = bh & 15;
    const int n1 = 2 * (j + 1), ns = 34;
    const long kvbase = (long)bh * 32 * 8192;   // short offset of tile 0 for this bh
    const int koff = hi * 256 + l31 * 8;        // lane offset within fragment chunks

    bf16x8 qf[8];
    auto loadq = [&](int qt_) {
        const int qrow = qt_ * 128 + w * 32 + l31;
        const float* qp = q + ((long)(b * SEQ + qrow) * Hh + h) * Dd + hi * 8;
#pragma unroll
        for (int kk = 0; kk < 8; ++kk) {
            float4 A = *(const float4*)(qp + kk * 16);
            float4 Bv = *(const float4*)(qp + kk * 16 + 4);
            A.x *= ATT_C; A.y *= ATT_C; A.z *= ATT_C; A.w *= ATT_C;
            Bv.x *= ATT_C; Bv.y *= ATT_C; Bv.z *= ATT_C; Bv.w *= ATT_C;
            union { uint4 u; bf16x8 v; } cv;
            cv.u = pack8(A, Bv);
            qf[kk] = cv.v;
        }
    };
    auto stage = [&](int nb, int t) {
        const ushort* kg = ek + kvbase + (long)t * 8192 + tid * 8;
        const ushort* vg = evt + kvbase + (long)t * 8192 + tid * 8;
        ushort* kl = &KV[nb][tid * 8];
        ushort* vl = &KV[nb][8192 + tid * 8];
#pragma unroll
        for (int i = 0; i < 4; ++i) {
            gll16(kg + i * 2048, kl + i * 2048);
            gll16(vg + i * 2048, vl + i * 2048);
        }
    };

    f32x16 o[4];
#pragma unroll
    for (int nt = 0; nt < 4; ++nt) o[nt] = zero16();
    float m = NEGINF, lsum = 0.f;

    stage(0, 0);
    loadq(j);
    __syncthreads();

    int cur = 0;
    int qt = j, qtb = qt * 128 + w * 32;

    for (int s = 0; s < ns; ++s) {
        if (s + 1 < ns) stage(cur ^ 1, (s + 1 < n1) ? s + 1 : s + 1 - n1);
        if (s == n1) { qt = 15 - j; qtb = qt * 128 + w * 32; loadq(qt); }
        const int kv0 = ((s < n1) ? s : s - n1) * 64;
        const int qpos = qtb + l31;
        const ushort* Kb = &KV[cur][0];
        const ushort* Vb = &KV[cur][8192];

        if (kv0 <= qtb + 31) {
            const bool h2full = (kv0 + 32 <= qtb + 31);  // second 32-key half live?
            f32x16 s0 = zero16(), s1;
            __builtin_amdgcn_s_setprio(1);
#pragma unroll
            for (int kk = 0; kk < 8; ++kk)
                s0 = __builtin_amdgcn_mfma_f32_32x32x16_bf16(
                    *(const bf16x8*)&Kb[kk * 512 + koff], qf[kk], s0, 0, 0, 0);
            if (h2full) {
                s1 = zero16();
#pragma unroll
                for (int kk = 0; kk < 8; ++kk)
                    s1 = __builtin_amdgcn_mfma_f32_32x32x16_bf16(
                        *(const bf16x8*)&Kb[4096 + kk * 512 + koff], qf[kk], s1, 0, 0, 0);
            }
            __builtin_amdgcn_s_setprio(0);

            // ---- causal mask + tile max (scale pre-folded into Q) ----
            float mt = NEGINF;
            const bool needmask = (kv0 + 63 > qtb);
            if (needmask) {
#pragma unroll
                for (int r = 0; r < 16; ++r) {
                    const int kr = kv0 + ((r & 3) + 8 * (r >> 2) + 4 * hi);
                    float a0 = (kr <= qpos) ? s0[r] : NEGINF;
                    s0[r] = a0;
                    mt = fmaxf(mt, a0);
                }
                if (h2full) {
#pragma unroll
                    for (int r = 0; r < 16; ++r) {
                        const int kr = kv0 + 32 + ((r & 3) + 8 * (r >> 2) + 4 * hi);
                        float a1 = (kr <= qpos) ? s1[r] : NEGINF;
                        s1[r] = a1;
                        mt = fmaxf(mt, a1);
                    }
                }
            } else {
#pragma unroll
                for (int r = 0; r < 16; ++r) mt = fmaxf(mt, fmaxf(s0[r], s1[r]));
            }
            mt = fmaxf(mt, __shfl_xor(mt, 32));

            // ---- defer-max rescale (THR=8 in log2 domain) ----
            if (!__all(mt <= m + 8.f)) {
                const float mn = fmaxf(m, mt);
                const float al = exp2f(m - mn);
                m = mn;
                lsum *= al;
#pragma unroll
                for (int r = 0; r < 16; ++r) {
                    const float alr = __shfl(al, (r & 3) + 8 * (r >> 2) + 4 * hi);
                    o[0][r] *= alr; o[1][r] *= alr; o[2][r] *= alr; o[3][r] *= alr;
                }
            }

            // ---- P = exp2(z - m), row sum ----
            float psum = 0.f;
#pragma unroll
            for (int r = 0; r < 16; ++r) {
                s0[r] = __builtin_amdgcn_exp2f(s0[r] - m);
                psum += s0[r];
            }
            if (h2full) {
#pragma unroll
                for (int r = 0; r < 16; ++r) {
                    s1[r] = __builtin_amdgcn_exp2f(s1[r] - m);
                    psum += s1[r];
                }
            }
            lsum += psum;

            // ---- pack P -> A-fragments ----
            bf16x8 pa00 = mkfrag(pkbf(s0[0], s0[1]), pkbf(s0[2], s0[3]),
                                 pkbf(s0[4], s0[5]), pkbf(s0[6], s0[7]), hi);
            bf16x8 pa01 = mkfrag(pkbf(s0[8], s0[9]), pkbf(s0[10], s0[11]),
                                 pkbf(s0[12], s0[13]), pkbf(s0[14], s0[15]), hi);
            __builtin_amdgcn_s_setprio(1);
#pragma unroll
            for (int nt = 0; nt < 4; ++nt) {
                const int vb = nt * 2048 + koff;
                o[nt] = __builtin_amdgcn_mfma_f32_32x32x16_bf16(
                    pa00, *(const bf16x8*)&Vb[vb], o[nt], 0, 0, 0);
                o[nt] = __builtin_amdgcn_mfma_f32_32x32x16_bf16(
                    pa01, *(const bf16x8*)&Vb[vb + 512], o[nt], 0, 0, 0);
            }
            __builtin_amdgcn_s_setprio(0);
            if (h2full) {
                bf16x8 pa10 = mkfrag(pkbf(s1[0], s1[1]), pkbf(s1[2], s1[3]),
                                     pkbf(s1[4], s1[5]), pkbf(s1[6], s1[7]), hi);
                bf16x8 pa11 = mkfrag(pkbf(s1[8], s1[9]), pkbf(s1[10], s1[11]),
                                     pkbf(s1[12], s1[13]), pkbf(s1[14], s1[15]), hi);
                __builtin_amdgcn_s_setprio(1);
#pragma unroll
                for (int nt = 0; nt < 4; ++nt) {
                    const int vb = nt * 2048 + koff;
                    o[nt] = __builtin_amdgcn_mfma_f32_32x32x16_bf16(
                        pa10, *(const bf16x8*)&Vb[vb + 1024], o[nt], 0, 0, 0);
                    o[nt] = __builtin_amdgcn_mfma_f32_32x32x16_bf16(
                        pa11, *(const bf16x8*)&Vb[vb + 1536], o[nt], 0, 0, 0);
                }
                __builtin_amdgcn_s_setprio(0);
            }
        }

        if (s == n1 - 1 || s == ns - 1) {
            // ---- epilogue for this qtile ----
            const float lt = lsum + __shfl_xor(lsum, 32);
            const float inv_ = 1.f / lt;
#pragma unroll
            for (int r = 0; r < 16; ++r) {
                const int qr = (r & 3) + 8 * (r >> 2) + 4 * hi;
                const float ivr = __shfl(inv_, qr);
                float* op = out + ((long)(b * SEQ + qtb + qr) * Hh + h) * Dd + l31;
                op[0]  = o[0][r] * ivr;
                op[32] = o[1][r] * ivr;
                op[64] = o[2][r] * ivr;
                op[96] = o[3][r] * ivr;
            }
#pragma unroll
            for (int nt = 0; nt < 4; ++nt) o[nt] = zero16();
            m = NEGINF; lsum = 0.f;
        }

        __syncthreads();   // drains vmcnt (next-tile gload_lds) + lgkmcnt
        cur ^= 1;
    }
}

extern "C" void kernel_launch(void* const* d_in, const int* in_sizes, int n_in,
                              void* d_out, int out_size, void* d_ws, size_t ws_size,
                              hipStream_t stream) {
    const float* q = (const float*)d_in[0];
    const float* k = (const float*)d_in[1];
    const float* v = (const float*)d_in[2];
    const float* k_cache = (const float*)d_in[3];
    const float* v_cache = (const float*)d_in[4];
    const int* slot_mapping = (const int*)d_in[5];
    float* out = (float*)d_out;

    const int T = in_sizes[0] / HD;  // 8192
    (void)n_in; (void)out_size; (void)ws_size;

    ushort* ek = (ushort*)d_ws;                 // fragment-major K tiles (32 MB)
    ushort* evt = ek + (size_t)T * HD;          // fragment-major V tiles (32 MB)
    int* inv = (int*)(evt + (size_t)T * HD);    // [T] inverse slot map

    initinv<<<T / 256, 256, 0, stream>>>(inv, T);
    buildinv<<<T / 256, 256, 0, stream>>>(slot_mapping, inv, T);
    fusekv<<<dim3(T / 64, Hh), 256, 0, stream>>>(k, v, k_cache, v_cache, inv, ek, evt);
    attn32<<<dim3(512), 256, 0, stream>>>(q, ek, evt, out);
}

// Round 5
// 153.591 us; speedup vs baseline: 3.0201x; 1.0360x over previous
//
#include <hip/hip_runtime.h>

typedef float f32x16 __attribute__((ext_vector_type(16)));
typedef __bf16 bf16x8 __attribute__((ext_vector_type(8)));
typedef unsigned int uint2v __attribute__((ext_vector_type(2)));

#define Hh 16
#define Dd 128
#define SEQ 2048
#define HD 2048                      // Hh*Dd
#define ATT_C 0.12751743f            // (1/sqrt(128)) * log2(e)
#define NEGINF (-__builtin_inff())

__device__ __forceinline__ ushort f2bf(float f) {
    uint u = __builtin_bit_cast(uint, f);
    return (ushort)((u + 0x7FFFu + ((u >> 16) & 1u)) >> 16);
}

__device__ __forceinline__ uint4 pack8(float4 a, float4 b) {
    uint4 u;
    u.x = (uint)f2bf(a.x) | ((uint)f2bf(a.y) << 16);
    u.y = (uint)f2bf(a.z) | ((uint)f2bf(a.w) << 16);
    u.z = (uint)f2bf(b.x) | ((uint)f2bf(b.y) << 16);
    u.w = (uint)f2bf(b.z) | ((uint)f2bf(b.w) << 16);
    return u;
}

// single-instruction packed f32->bf16 (RNE), low=a high=b
__device__ __forceinline__ uint cvtpk(float a, float b) {
    uint r;
    asm("v_cvt_pk_bf16_f32 %0, %1, %2" : "=v"(r) : "v"(a), "v"(b));
    return r;
}

__device__ __forceinline__ f32x16 zero16() {
    f32x16 v;
#pragma unroll
    for (int i = 0; i < 16; ++i) v[i] = 0.f;
    return v;
}

// async global->LDS, 16 B per lane (dest must be tid-linear)
__device__ __forceinline__ void gll16(const void* g, void* l) {
    __builtin_amdgcn_global_load_lds(
        (const __attribute__((address_space(1))) unsigned int*)g,
        (__attribute__((address_space(3))) unsigned int*)l, 16, 0, 0);
}

// PV A-fragment assembly via permlane32_swap (verified R2/R4)
__device__ __forceinline__ bf16x8 mkfrag(uint a01, uint a23, uint a45, uint a67, int hi) {
    uint4 u;
#if __has_builtin(__builtin_amdgcn_permlane32_swap)
    uint2v xz = __builtin_amdgcn_permlane32_swap(a01, a45, false, false);
    uint2v yw = __builtin_amdgcn_permlane32_swap(a23, a67, false, false);
    u.x = xz[0]; u.y = yw[0]; u.z = xz[1]; u.w = yw[1];
    (void)hi;
#else
    uint s01 = __shfl_xor(a01, 32), s23 = __shfl_xor(a23, 32);
    uint s45 = __shfl_xor(a45, 32), s67 = __shfl_xor(a67, 32);
    u.x = hi ? s45 : a01;
    u.y = hi ? s67 : a23;
    u.z = hi ? a45 : s01;
    u.w = hi ? a67 : s23;
#endif
    return __builtin_bit_cast(bf16x8, u);
}

// ---- inverse slot map ----
__global__ void initinv(int* __restrict__ inv, int T) {
    int i = blockIdx.x * 256 + threadIdx.x;
    if (i < T) inv[i] = -1;
}
__global__ void buildinv(const int* __restrict__ slots, int* __restrict__ inv, int T) {
    int t = blockIdx.x * 256 + threadIdx.x;
    if (t < T) { int s = slots[t]; if (s >= 0 && s < T) inv[s] = t; }
}

// ---- fused effective-KV materialization into FRAGMENT-MAJOR 16KB tiles ----
// K tile chunk c = (half*16 + j)*32 + l : 16B = K[key=half*32+l][d=j*8..j*8+7]
// V tile chunk c = (nt*8 + ch)*32 + l   : 16B = V[key=ch*8..+7][d=nt*32+l]
__global__ void fusekv(const float* __restrict__ k, const float* __restrict__ v,
                       const float* __restrict__ kc, const float* __restrict__ vc,
                       const int* __restrict__ inv, ushort* __restrict__ ek,
                       ushort* __restrict__ evt) {
    __shared__ int sv[64];
    __shared__ ushort Ks[64][136];
    __shared__ ushort Lt[128][72];
    const int tid = threadIdx.x;
    const int r0 = blockIdx.x * 64, h = blockIdx.y;
    const int b = r0 >> 11, tok0 = r0 & (SEQ - 1);
    const long tb = ((long)(b * Hh + h) * 32 + (tok0 >> 6)) * 8192;
    if (tid < 64) sv[tid] = inv[r0 + tid];
    __syncthreads();
#pragma unroll
    for (int i = 0; i < 4; ++i) {
        int idx = i * 256 + tid, r = idx >> 4, sg = idx & 15;
        int s = sv[r];
        const float* src = (s >= 0 ? k + (long)s * HD : kc + (long)(r0 + r) * HD) + h * Dd + sg * 8;
        float4 A = *(const float4*)src;
        float4 Bv = *(const float4*)(src + 4);
        *(uint4*)&Ks[r][sg * 8] = pack8(A, Bv);
    }
    const int d = tid & 127, hf2 = tid >> 7;
#pragma unroll
    for (int i = 0; i < 8; ++i) {
        const int t = i * 8 + hf2 * 4;
        ushort wv[4];
#pragma unroll
        for (int jj = 0; jj < 4; ++jj) {
            int s = sv[t + jj];
            const float* sp = (s >= 0 ? v + (long)s * HD : vc + (long)(r0 + t + jj) * HD) + h * Dd + d;
            wv[jj] = f2bf(*sp);
        }
        uint2 u;
        u.x = (uint)wv[0] | ((uint)wv[1] << 16);
        u.y = (uint)wv[2] | ((uint)wv[3] << 16);
        *(uint2*)&Lt[d][t] = u;
    }
    __syncthreads();
#pragma unroll
    for (int i = 0; i < 4; ++i) {
        int c = i * 256 + tid, l = c & 31, j = (c >> 5) & 15, hf = c >> 9;
        *(uint4*)(ek + tb + (long)c * 8) = *(const uint4*)&Ks[hf * 32 + l][j * 8];
    }
#pragma unroll
    for (int i = 0; i < 4; ++i) {
        int c = i * 256 + tid, l = c & 31, ch = (c >> 5) & 7, nt = c >> 8;
        *(uint4*)(evt + tb + (long)c * 8) = *(const uint4*)&Lt[nt * 32 + l][ch * 8];
    }
}

// ---- causal flash attention: 8 waves / 256-row qtile, shared KV dbuf ----
__global__ __launch_bounds__(512, 2) void attn32(const float* __restrict__ q,
                                                 const ushort* __restrict__ ek,
                                                 const ushort* __restrict__ evt,
                                                 float* __restrict__ out) {
    __shared__ ushort KV[2][16384];  // [buf][ K tile 8192 | V tile 8192 ] shorts

    const int tid = threadIdx.x;
    const int w = tid >> 6, lane = tid & 63;
    const int l31 = lane & 31, hi = lane >> 5;
    const int g = blockIdx.x;
    const int bh = g & 63, jp = g >> 6;   // all 4 pair-blocks of a bh on XCD bh%8
    const int b = bh >> 4, h = bh & 15;
    const int n1 = 4 * (jp + 1), ns = 36; // phase1: qtile jp, phase2: qtile 7-jp
    const long kvbase = (long)bh * 32 * 8192;
    const int koff = hi * 256 + l31 * 8;

    bf16x8 qf[8];
    auto loadq = [&](int qt_) {
        const int qrow = qt_ * 256 + w * 32 + l31;
        const float* qp = q + ((long)(b * SEQ + qrow) * Hh + h) * Dd + hi * 8;
#pragma unroll
        for (int kk = 0; kk < 8; ++kk) {
            float4 A = *(const float4*)(qp + kk * 16);
            float4 Bv = *(const float4*)(qp + kk * 16 + 4);
            A.x *= ATT_C; A.y *= ATT_C; A.z *= ATT_C; A.w *= ATT_C;
            Bv.x *= ATT_C; Bv.y *= ATT_C; Bv.z *= ATT_C; Bv.w *= ATT_C;
            union { uint4 u; bf16x8 v; } cv;
            cv.u = pack8(A, Bv);
            qf[kk] = cv.v;
        }
    };
    auto stage = [&](int nb, int t) {
        const ushort* kg = ek + kvbase + (long)t * 8192 + tid * 8;
        const ushort* vg = evt + kvbase + (long)t * 8192 + tid * 8;
        ushort* kl = &KV[nb][tid * 8];
        ushort* vl = &KV[nb][8192 + tid * 8];
#pragma unroll
        for (int i = 0; i < 2; ++i) {
            gll16(kg + i * 4096, kl + i * 4096);
            gll16(vg + i * 4096, vl + i * 4096);
        }
    };

    f32x16 o[4];
#pragma unroll
    for (int nt = 0; nt < 4; ++nt) o[nt] = zero16();
    float m = NEGINF, lsum = 0.f;

    stage(0, 0);
    loadq(jp);
    __syncthreads();

    int cur = 0;
    int qt = jp, qtb = qt * 256 + w * 32;

    for (int s = 0; s < ns; ++s) {
        if (s + 1 < ns) stage(cur ^ 1, (s + 1 < n1) ? s + 1 : s + 1 - n1);
        if (s == n1) { qt = 7 - jp; qtb = qt * 256 + w * 32; loadq(qt); }
        const int kv0 = ((s < n1) ? s : s - n1) * 64;
        const int qpos = qtb + l31;
        const ushort* Kb = &KV[cur][0];
        const ushort* Vb = &KV[cur][8192];

        if (kv0 <= qtb + 31) {
            const bool h2full = (kv0 + 32 <= qtb + 31);
            f32x16 s0 = zero16(), s1;
            __builtin_amdgcn_s_setprio(1);
            if (h2full) {
                s1 = zero16();
#pragma unroll
                for (int kk = 0; kk < 8; ++kk) {  // two independent chains
                    s0 = __builtin_amdgcn_mfma_f32_32x32x16_bf16(
                        *(const bf16x8*)&Kb[kk * 512 + koff], qf[kk], s0, 0, 0, 0);
                    s1 = __builtin_amdgcn_mfma_f32_32x32x16_bf16(
                        *(const bf16x8*)&Kb[4096 + kk * 512 + koff], qf[kk], s1, 0, 0, 0);
                }
            } else {
#pragma unroll
                for (int kk = 0; kk < 8; ++kk)
                    s0 = __builtin_amdgcn_mfma_f32_32x32x16_bf16(
                        *(const bf16x8*)&Kb[kk * 512 + koff], qf[kk], s0, 0, 0, 0);
            }
            __builtin_amdgcn_s_setprio(0);

            // ---- causal mask + tile max (scale pre-folded into Q) ----
            float mt = NEGINF;
            const bool needmask = (kv0 + 63 > qtb);
            if (needmask) {
#pragma unroll
                for (int r = 0; r < 16; ++r) {
                    const int kr = kv0 + ((r & 3) + 8 * (r >> 2) + 4 * hi);
                    float a0 = (kr <= qpos) ? s0[r] : NEGINF;
                    s0[r] = a0;
                    mt = fmaxf(mt, a0);
                }
                if (h2full) {
#pragma unroll
                    for (int r = 0; r < 16; ++r) {
                        const int kr = kv0 + 32 + ((r & 3) + 8 * (r >> 2) + 4 * hi);
                        float a1 = (kr <= qpos) ? s1[r] : NEGINF;
                        s1[r] = a1;
                        mt = fmaxf(mt, a1);
                    }
                }
            } else {
#pragma unroll
                for (int r = 0; r < 16; ++r) mt = fmaxf(mt, fmaxf(s0[r], s1[r]));
            }
            mt = fmaxf(mt, __shfl_xor(mt, 32));

            // ---- defer-max rescale (THR=8 in log2 domain) ----
            if (!__all(mt <= m + 8.f)) {
                const float mn = fmaxf(m, mt);
                const float al = exp2f(m - mn);
                m = mn;
                lsum *= al;
#pragma unroll
                for (int r = 0; r < 16; ++r) {
                    const float alr = __shfl(al, (r & 3) + 8 * (r >> 2) + 4 * hi);
                    o[0][r] *= alr; o[1][r] *= alr; o[2][r] *= alr; o[3][r] *= alr;
                }
            }

            // ---- P = exp2(z - m), row sum ----
            float psum = 0.f;
#pragma unroll
            for (int r = 0; r < 16; ++r) {
                s0[r] = __builtin_amdgcn_exp2f(s0[r] - m);
                psum += s0[r];
            }
            if (h2full) {
#pragma unroll
                for (int r = 0; r < 16; ++r) {
                    s1[r] = __builtin_amdgcn_exp2f(s1[r] - m);
                    psum += s1[r];
                }
            }
            lsum += psum;

            // ---- pack P -> A-fragments (v_cvt_pk_bf16_f32 + permlane) ----
            bf16x8 pa00 = mkfrag(cvtpk(s0[0], s0[1]), cvtpk(s0[2], s0[3]),
                                 cvtpk(s0[4], s0[5]), cvtpk(s0[6], s0[7]), hi);
            bf16x8 pa01 = mkfrag(cvtpk(s0[8], s0[9]), cvtpk(s0[10], s0[11]),
                                 cvtpk(s0[12], s0[13]), cvtpk(s0[14], s0[15]), hi);
            __builtin_amdgcn_s_setprio(1);
#pragma unroll
            for (int nt = 0; nt < 4; ++nt) {
                const int vb = nt * 2048 + koff;
                o[nt] = __builtin_amdgcn_mfma_f32_32x32x16_bf16(
                    pa00, *(const bf16x8*)&Vb[vb], o[nt], 0, 0, 0);
                o[nt] = __builtin_amdgcn_mfma_f32_32x32x16_bf16(
                    pa01, *(const bf16x8*)&Vb[vb + 512], o[nt], 0, 0, 0);
            }
            __builtin_amdgcn_s_setprio(0);
            if (h2full) {
                bf16x8 pa10 = mkfrag(cvtpk(s1[0], s1[1]), cvtpk(s1[2], s1[3]),
                                     cvtpk(s1[4], s1[5]), cvtpk(s1[6], s1[7]), hi);
                bf16x8 pa11 = mkfrag(cvtpk(s1[8], s1[9]), cvtpk(s1[10], s1[11]),
                                     cvtpk(s1[12], s1[13]), cvtpk(s1[14], s1[15]), hi);
                __builtin_amdgcn_s_setprio(1);
#pragma unroll
                for (int nt = 0; nt < 4; ++nt) {
                    const int vb = nt * 2048 + koff;
                    o[nt] = __builtin_amdgcn_mfma_f32_32x32x16_bf16(
                        pa10, *(const bf16x8*)&Vb[vb + 1024], o[nt], 0, 0, 0);
                    o[nt] = __builtin_amdgcn_mfma_f32_32x32x16_bf16(
                        pa11, *(const bf16x8*)&Vb[vb + 1536], o[nt], 0, 0, 0);
                }
                __builtin_amdgcn_s_setprio(0);
            }
        }

        if (s == n1 - 1 || s == ns - 1) {
            const float lt = lsum + __shfl_xor(lsum, 32);
            const float inv_ = 1.f / lt;
#pragma unroll
            for (int r = 0; r < 16; ++r) {
                const int qr = (r & 3) + 8 * (r >> 2) + 4 * hi;
                const float ivr = __shfl(inv_, qr);
                float* op = out + ((long)(b * SEQ + qtb + qr) * Hh + h) * Dd + l31;
                op[0]  = o[0][r] * ivr;
                op[32] = o[1][r] * ivr;
                op[64] = o[2][r] * ivr;
                op[96] = o[3][r] * ivr;
            }
#pragma unroll
            for (int nt = 0; nt < 4; ++nt) o[nt] = zero16();
            m = NEGINF; lsum = 0.f;
        }

        __syncthreads();   // drains own gload_lds (issued a full step ago) + publishes buffers
        cur ^= 1;
    }
}

extern "C" void kernel_launch(void* const* d_in, const int* in_sizes, int n_in,
                              void* d_out, int out_size, void* d_ws, size_t ws_size,
                              hipStream_t stream) {
    const float* q = (const float*)d_in[0];
    const float* k = (const float*)d_in[1];
    const float* v = (const float*)d_in[2];
    const float* k_cache = (const float*)d_in[3];
    const float* v_cache = (const float*)d_in[4];
    const int* slot_mapping = (const int*)d_in[5];
    float* out = (float*)d_out;

    const int T = in_sizes[0] / HD;  // 8192
    (void)n_in; (void)out_size; (void)ws_size;

    ushort* ek = (ushort*)d_ws;                 // fragment-major K tiles (32 MB)
    ushort* evt = ek + (size_t)T * HD;          // fragment-major V tiles (32 MB)
    int* inv = (int*)(evt + (size_t)T * HD);    // [T] inverse slot map

    initinv<<<T / 256, 256, 0, stream>>>(inv, T);
    buildinv<<<T / 256, 256, 0, stream>>>(slot_mapping, inv, T);
    fusekv<<<dim3(T / 64, Hh), 256, 0, stream>>>(k, v, k_cache, v_cache, inv, ek, evt);
    attn32<<<dim3(256), 512, 0, stream>>>(q, ek, evt, out);
}